// Round 2
// baseline (2206.753 us; speedup 1.0000x reference)
//
#include <hip/hip_runtime.h>

// Edge softmax, round 2: atomic-contention attack.
//   - workspace accumulators transposed to [H][N] (8 head-updates of one edge
//     hit 8 distinct far-apart cache lines instead of one line)
//   - R-way replicated accumulators keyed by blockIdx (default R=8 ~ XCD id)
//   - one thread per EDGE, float4x2 vectorized logits/scores
// Pipeline:
//   memset(menc, ssum) -> pass1 (8x atomicMax/edge) -> reduce_max ->
//   pass2 (8x atomicAdd/edge, scores store) -> finalize_norm (transpose to [N,H])

__device__ __forceinline__ unsigned enc_f32(float f) {
    unsigned u = __float_as_uint(f);
    return (u & 0x80000000u) ? ~u : (u | 0x80000000u);
}
__device__ __forceinline__ float dec_f32(unsigned u) {
    return __uint_as_float((u & 0x80000000u) ? (u & 0x7FFFFFFFu) : ~u);
}

// ---------- H == 8 fast path ----------

__global__ __launch_bounds__(256)
void pass1_max8(const float* __restrict__ logits, const int* __restrict__ dst,
                unsigned* __restrict__ menc, int E, int N, int Rmask) {
    int e = blockIdx.x * 256 + threadIdx.x;
    if (e >= E) return;
    int d = dst[e];
    const float4* lp = (const float4*)(logits + (size_t)e * 8);
    float4 a = lp[0], b = lp[1];
    unsigned* base = menc + (size_t)(blockIdx.x & Rmask) * 8 * N + d;
    atomicMax(base + 0 * (size_t)N, enc_f32(a.x));
    atomicMax(base + 1 * (size_t)N, enc_f32(a.y));
    atomicMax(base + 2 * (size_t)N, enc_f32(a.z));
    atomicMax(base + 3 * (size_t)N, enc_f32(a.w));
    atomicMax(base + 4 * (size_t)N, enc_f32(b.x));
    atomicMax(base + 5 * (size_t)N, enc_f32(b.y));
    atomicMax(base + 6 * (size_t)N, enc_f32(b.z));
    atomicMax(base + 7 * (size_t)N, enc_f32(b.w));
}

__global__ void reduce_max_k(const unsigned* __restrict__ menc,
                             unsigned* __restrict__ mfin, int NH, int R) {
    int j = blockIdx.x * blockDim.x + threadIdx.x;   // j = h*N + n
    if (j >= NH) return;
    unsigned m = menc[j];
    for (int r = 1; r < R; ++r) m = max(m, menc[(size_t)r * NH + j]);
    mfin[j] = m;
}

__global__ __launch_bounds__(256)
void pass2_score8(const float* __restrict__ logits, const int* __restrict__ dst,
                  const unsigned* __restrict__ mfin, float* __restrict__ scores,
                  float* __restrict__ ssum, int E, int N, int Rmask) {
    int e = blockIdx.x * 256 + threadIdx.x;
    if (e >= E) return;
    int d = dst[e];
    const float4* lp = (const float4*)(logits + (size_t)e * 8);
    float4 a = lp[0], b = lp[1];
    float s0 = __expf(a.x - dec_f32(mfin[0 * (size_t)N + d]));
    float s1 = __expf(a.y - dec_f32(mfin[1 * (size_t)N + d]));
    float s2 = __expf(a.z - dec_f32(mfin[2 * (size_t)N + d]));
    float s3 = __expf(a.w - dec_f32(mfin[3 * (size_t)N + d]));
    float s4 = __expf(b.x - dec_f32(mfin[4 * (size_t)N + d]));
    float s5 = __expf(b.y - dec_f32(mfin[5 * (size_t)N + d]));
    float s6 = __expf(b.z - dec_f32(mfin[6 * (size_t)N + d]));
    float s7 = __expf(b.w - dec_f32(mfin[7 * (size_t)N + d]));
    float4* sp = (float4*)(scores + (size_t)e * 8);
    sp[0] = make_float4(s0, s1, s2, s3);
    sp[1] = make_float4(s4, s5, s6, s7);
    float* base = ssum + (size_t)(blockIdx.x & Rmask) * 8 * N + d;
    atomicAdd(base + 0 * (size_t)N, s0);
    atomicAdd(base + 1 * (size_t)N, s1);
    atomicAdd(base + 2 * (size_t)N, s2);
    atomicAdd(base + 3 * (size_t)N, s3);
    atomicAdd(base + 4 * (size_t)N, s4);
    atomicAdd(base + 5 * (size_t)N, s5);
    atomicAdd(base + 6 * (size_t)N, s6);
    atomicAdd(base + 7 * (size_t)N, s7);
}

__global__ void finalize_norm_k(const float* __restrict__ ssum,
                                float* __restrict__ norm,
                                int NH, int N, int H, int R) {
    int j = blockIdx.x * blockDim.x + threadIdx.x;   // j = h*N + n
    if (j >= NH) return;
    float s = ssum[j];
    for (int r = 1; r < R; ++r) s += ssum[(size_t)r * NH + j];
    int h = j / N;
    int n = j - h * N;
    norm[(size_t)n * H + h] = s;
}

// ---------- generic-H fallback (scalar) ----------

__global__ void pass1_max_g(const float* __restrict__ logits, const int* __restrict__ dst,
                            unsigned* __restrict__ menc, int E, int N, int H, int Rmask) {
    int e = blockIdx.x * blockDim.x + threadIdx.x;
    if (e >= E) return;
    int d = dst[e];
    unsigned* base = menc + (size_t)(blockIdx.x & Rmask) * H * N + d;
    for (int h = 0; h < H; ++h)
        atomicMax(base + (size_t)h * N, enc_f32(logits[(size_t)e * H + h]));
}

__global__ void pass2_score_g(const float* __restrict__ logits, const int* __restrict__ dst,
                              const unsigned* __restrict__ mfin, float* __restrict__ scores,
                              float* __restrict__ ssum, int E, int N, int H, int Rmask) {
    int e = blockIdx.x * blockDim.x + threadIdx.x;
    if (e >= E) return;
    int d = dst[e];
    float* base = ssum + (size_t)(blockIdx.x & Rmask) * H * N + d;
    for (int h = 0; h < H; ++h) {
        float s = __expf(logits[(size_t)e * H + h] - dec_f32(mfin[(size_t)h * N + d]));
        scores[(size_t)e * H + h] = s;
        atomicAdd(base + (size_t)h * N, s);
    }
}

// ---------- round-1 style fallback for tiny workspace ----------

__global__ void pass2_old(const float* __restrict__ logits, const int* __restrict__ dst,
                          const unsigned* __restrict__ menc, float* __restrict__ scores,
                          float* __restrict__ norm, int EH, int H) {
    int i = blockIdx.x * blockDim.x + threadIdx.x;
    if (i >= EH) return;
    int e = i / H, h = i - e * H;
    int d = dst[e];
    float s = __expf(logits[i] - dec_f32(menc[(size_t)h * (size_t)0 + (size_t)d * H + h]));
    scores[i] = s;
    atomicAdd(norm + (size_t)d * H + h, s);
}
__global__ void pass1_old(const float* __restrict__ logits, const int* __restrict__ dst,
                          unsigned* __restrict__ menc, int EH, int H) {
    int i = blockIdx.x * blockDim.x + threadIdx.x;
    if (i >= EH) return;
    int e = i / H, h = i - e * H;
    atomicMax(menc + (size_t)dst[e] * H + h, enc_f32(logits[i]));
}
__global__ void pass2_old2(const float* __restrict__ logits, const int* __restrict__ dst,
                           const unsigned* __restrict__ menc, float* __restrict__ scores,
                           float* __restrict__ norm, int EH, int H) {
    int i = blockIdx.x * blockDim.x + threadIdx.x;
    if (i >= EH) return;
    int e = i / H, h = i - e * H;
    int d = dst[e];
    float s = __expf(logits[i] - dec_f32(menc[(size_t)d * H + h]));
    scores[i] = s;
    atomicAdd(norm + (size_t)d * H + h, s);
}

extern "C" void kernel_launch(void* const* d_in, const int* in_sizes, int n_in,
                              void* d_out, int out_size, void* d_ws, size_t ws_size,
                              hipStream_t stream) {
    const float* logits = (const float*)d_in[0];   // [E, H, 1] f32
    const int*   dst    = (const int*)d_in[1];     // [E] i32

    const int EH = in_sizes[0];
    const int E  = in_sizes[1];
    const int H  = EH / E;
    const int NH = out_size - EH;
    const int N  = NH / H;

    float* scores = (float*)d_out;          // [E,H]
    float* norm   = scores + EH;            // [N,H]

    const size_t nhb = (size_t)NH * 4;

    if (ws_size < 2 * nhb) {
        // tiny workspace: round-1 scheme (menc only, atomics straight into d_out)
        unsigned* menc = (unsigned*)d_ws;
        hipMemsetAsync(menc, 0, nhb, stream);
        hipMemsetAsync(norm, 0, nhb, stream);
        int block = 256, grid = (EH + block - 1) / block;
        pass1_old<<<grid, block, 0, stream>>>(logits, dst, menc, EH, H);
        pass2_old2<<<grid, block, 0, stream>>>(logits, dst, menc, scores, norm, EH, H);
        return;
    }

    // pick largest replica count R in {8,4,2,1} with (2R+1)*NH*4 <= ws_size
    int R = 1;
    for (int cand = 8; cand >= 1; cand >>= 1) {
        size_t need = (cand == 1) ? 2 * nhb : (size_t)(2 * cand + 1) * nhb;
        if (need <= ws_size) { R = cand; break; }
    }

    unsigned* menc = (unsigned*)d_ws;                 // [R][H][N]
    float*    ssum = (float*)((char*)d_ws + (size_t)R * nhb);        // [R][H][N]
    unsigned* mfin = (R == 1) ? menc
                              : (unsigned*)((char*)d_ws + (size_t)2 * R * nhb); // [H][N]

    hipMemsetAsync(menc, 0, (size_t)R * nhb, stream);
    hipMemsetAsync(ssum, 0, (size_t)R * nhb, stream);

    const int Rmask = R - 1;
    const int block = 256;
    const int gridE  = (E + block - 1) / block;
    const int gridNH = (NH + block - 1) / block;

    if (H == 8) {
        pass1_max8<<<gridE, block, 0, stream>>>(logits, dst, menc, E, N, Rmask);
        if (R > 1) reduce_max_k<<<gridNH, block, 0, stream>>>(menc, mfin, NH, R);
        pass2_score8<<<gridE, block, 0, stream>>>(logits, dst, mfin, scores, ssum, E, N, Rmask);
        finalize_norm_k<<<gridNH, block, 0, stream>>>(ssum, norm, NH, N, H, R);
    } else {
        pass1_max_g<<<gridE, block, 0, stream>>>(logits, dst, menc, E, N, H, Rmask);
        if (R > 1) reduce_max_k<<<gridNH, block, 0, stream>>>(menc, mfin, NH, R);
        pass2_score_g<<<gridE, block, 0, stream>>>(logits, dst, mfin, scores, ssum, E, N, H, Rmask);
        finalize_norm_k<<<gridNH, block, 0, stream>>>(ssum, norm, NH, N, H, R);
    }
}

// Round 3
// 555.188 us; speedup vs baseline: 3.9748x; 3.9748x over previous
//
#include <hip/hip_runtime.h>

// Edge softmax, round 3: CSR build + node-centric reduction (no atomics in the
// heavy pass).
//
// Round-2 lesson (counters): scattered atomic destinations write through 32B
// per atomic and serialize at the coherence point (898MB WRITE, 8x slowdown).
// Round-1 lesson: compact-layout atomics cap at ~170-190G atomics/s -> the
// only lever is atomic COUNT.
//
// Pipeline:
//   memset(counts)                         0.4 MB
//   k_hist    : counts[dst[e]]++           3.2M atomics on 400KB (compact)
//   k_scan1/2/3 : exclusive scan -> row_start, row_cur
//   k_scatter : perm[atomicAdd(row_cur[d])] = e   3.2M atomics
//   k_node    : wave per node; gather edges, butterfly max per head, exp,
//               store scores, butterfly sum, store norm. ZERO atomics.

__device__ __forceinline__ unsigned enc_f32(float f) {
    unsigned u = __float_as_uint(f);
    return (u & 0x80000000u) ? ~u : (u | 0x80000000u);
}
__device__ __forceinline__ float dec_f32(unsigned u) {
    return __uint_as_float((u & 0x80000000u) ? (u & 0x7FFFFFFFu) : ~u);
}

#define SCAN_B 256

__global__ __launch_bounds__(256)
void k_hist(const int* __restrict__ dst, unsigned* __restrict__ counts, int E) {
    int e = blockIdx.x * 256 + threadIdx.x;
    if (e < E) atomicAdd(&counts[dst[e]], 1u);
}

// per-block exclusive scan of counts -> row_start; block sums -> partials
__global__ __launch_bounds__(SCAN_B)
void k_scan1(const unsigned* __restrict__ counts, unsigned* __restrict__ row_start,
             unsigned* __restrict__ partials, int N) {
    __shared__ unsigned tmp[SCAN_B];
    int j = blockIdx.x * SCAN_B + threadIdx.x;
    unsigned v = (j < N) ? counts[j] : 0u;
    tmp[threadIdx.x] = v;
    __syncthreads();
    for (int off = 1; off < SCAN_B; off <<= 1) {
        unsigned t = (threadIdx.x >= off) ? tmp[threadIdx.x - off] : 0u;
        __syncthreads();
        tmp[threadIdx.x] += t;
        __syncthreads();
    }
    if (j < N) row_start[j] = tmp[threadIdx.x] - v;   // exclusive within block
    if (threadIdx.x == SCAN_B - 1) partials[blockIdx.x] = tmp[SCAN_B - 1];
}

// single-block exclusive scan of partials (carry loop, any nb)
__global__ __launch_bounds__(1024)
void k_scan2(unsigned* __restrict__ partials, int nb) {
    __shared__ unsigned tmp[1024];
    __shared__ unsigned carry_s;
    if (threadIdx.x == 0) carry_s = 0u;
    __syncthreads();
    for (int base = 0; base < nb; base += 1024) {
        int j = base + threadIdx.x;
        unsigned v = (j < nb) ? partials[j] : 0u;
        tmp[threadIdx.x] = v;
        __syncthreads();
        for (int off = 1; off < 1024; off <<= 1) {
            unsigned t = (threadIdx.x >= off) ? tmp[threadIdx.x - off] : 0u;
            __syncthreads();
            tmp[threadIdx.x] += t;
            __syncthreads();
        }
        unsigned incl  = tmp[threadIdx.x];
        unsigned total = tmp[1023];
        if (j < nb) partials[j] = incl - v + carry_s;  // exclusive + carry
        __syncthreads();
        if (threadIdx.x == 0) carry_s += total;
        __syncthreads();
    }
}

// add scanned block offsets; init row_cur
__global__ __launch_bounds__(SCAN_B)
void k_scan3(unsigned* __restrict__ row_start, const unsigned* __restrict__ partials,
             unsigned* __restrict__ row_cur, int N) {
    int j = blockIdx.x * SCAN_B + threadIdx.x;
    if (j < N) {
        unsigned v = row_start[j] + partials[blockIdx.x];
        row_start[j] = v;
        row_cur[j]   = v;
    }
}

__global__ __launch_bounds__(256)
void k_scatter(const int* __restrict__ dst, unsigned* __restrict__ row_cur,
               unsigned* __restrict__ perm, int E) {
    int e = blockIdx.x * 256 + threadIdx.x;
    if (e < E) {
        unsigned p = atomicAdd(&row_cur[dst[e]], 1u);
        perm[p] = (unsigned)e;
    }
}

// one wave per node: gather edges, per-head max (butterfly), exp, store scores,
// per-head sum (butterfly), store norm[n*8..n*8+7].
__global__ __launch_bounds__(256)
void k_node(const float* __restrict__ logits, const unsigned* __restrict__ perm,
            const unsigned* __restrict__ row_start, const unsigned* __restrict__ counts,
            float* __restrict__ scores, float* __restrict__ norm, int N) {
    int wid  = (blockIdx.x * 256 + threadIdx.x) >> 6;
    int lane = threadIdx.x & 63;
    if (wid >= N) return;
    unsigned start = row_start[wid];
    unsigned deg   = counts[wid];

    float z[8];
    float m[8];
#pragma unroll
    for (int h = 0; h < 8; ++h) m[h] = -INFINITY;

    bool single = (deg <= 64u);
    unsigned eid0 = 0u;

    if (single) {
        if (lane < (int)deg) {
            eid0 = perm[start + lane];
            const float4* lp = (const float4*)(logits + (size_t)eid0 * 8);
            float4 x = lp[0], y = lp[1];
            z[0] = x.x; z[1] = x.y; z[2] = x.z; z[3] = x.w;
            z[4] = y.x; z[5] = y.y; z[6] = y.z; z[7] = y.w;
#pragma unroll
            for (int h = 0; h < 8; ++h) m[h] = z[h];
        }
    } else {
        for (unsigned c = lane; c < deg; c += 64u) {
            unsigned eid = perm[start + c];
            const float4* lp = (const float4*)(logits + (size_t)eid * 8);
            float4 x = lp[0], y = lp[1];
            m[0] = fmaxf(m[0], x.x); m[1] = fmaxf(m[1], x.y);
            m[2] = fmaxf(m[2], x.z); m[3] = fmaxf(m[3], x.w);
            m[4] = fmaxf(m[4], y.x); m[5] = fmaxf(m[5], y.y);
            m[6] = fmaxf(m[6], y.z); m[7] = fmaxf(m[7], y.w);
        }
    }

    // butterfly max across the wave, all 8 heads
#pragma unroll
    for (int off = 1; off < 64; off <<= 1) {
#pragma unroll
        for (int h = 0; h < 8; ++h)
            m[h] = fmaxf(m[h], __shfl_xor(m[h], off));
    }

    float acc[8];
#pragma unroll
    for (int h = 0; h < 8; ++h) acc[h] = 0.0f;

    if (single) {
        if (lane < (int)deg) {
            float s[8];
#pragma unroll
            for (int h = 0; h < 8; ++h) { s[h] = __expf(z[h] - m[h]); acc[h] = s[h]; }
            float4* sp = (float4*)(scores + (size_t)eid0 * 8);
            sp[0] = make_float4(s[0], s[1], s[2], s[3]);
            sp[1] = make_float4(s[4], s[5], s[6], s[7]);
        }
    } else {
        for (unsigned c = lane; c < deg; c += 64u) {
            unsigned eid = perm[start + c];
            const float4* lp = (const float4*)(logits + (size_t)eid * 8);
            float4 x = lp[0], y = lp[1];
            float s0 = __expf(x.x - m[0]), s1 = __expf(x.y - m[1]);
            float s2 = __expf(x.z - m[2]), s3 = __expf(x.w - m[3]);
            float s4 = __expf(y.x - m[4]), s5 = __expf(y.y - m[5]);
            float s6 = __expf(y.z - m[6]), s7 = __expf(y.w - m[7]);
            float4* sp = (float4*)(scores + (size_t)eid * 8);
            sp[0] = make_float4(s0, s1, s2, s3);
            sp[1] = make_float4(s4, s5, s6, s7);
            acc[0] += s0; acc[1] += s1; acc[2] += s2; acc[3] += s3;
            acc[4] += s4; acc[5] += s5; acc[6] += s6; acc[7] += s7;
        }
    }

    // butterfly sum across the wave
#pragma unroll
    for (int off = 1; off < 64; off <<= 1) {
#pragma unroll
        for (int h = 0; h < 8; ++h)
            acc[h] += __shfl_xor(acc[h], off);
    }

    if (lane == 0) {
        float4* np = (float4*)(norm + (size_t)wid * 8);
        np[0] = make_float4(acc[0], acc[1], acc[2], acc[3]);
        np[1] = make_float4(acc[4], acc[5], acc[6], acc[7]);
    }
}

// ---------- round-1 fallback (small workspace or H != 8) ----------

__global__ void pass1_old(const float* __restrict__ logits, const int* __restrict__ dst,
                          unsigned* __restrict__ menc, int EH, int H) {
    int i = blockIdx.x * blockDim.x + threadIdx.x;
    if (i >= EH) return;
    int e = i / H, h = i - e * H;
    atomicMax(menc + (size_t)dst[e] * H + h, enc_f32(logits[i]));
}
__global__ void pass2_old(const float* __restrict__ logits, const int* __restrict__ dst,
                          const unsigned* __restrict__ menc, float* __restrict__ scores,
                          float* __restrict__ norm, int EH, int H) {
    int i = blockIdx.x * blockDim.x + threadIdx.x;
    if (i >= EH) return;
    int e = i / H, h = i - e * H;
    int d = dst[e];
    float s = __expf(logits[i] - dec_f32(menc[(size_t)d * H + h]));
    scores[i] = s;
    atomicAdd(norm + (size_t)d * H + h, s);
}

extern "C" void kernel_launch(void* const* d_in, const int* in_sizes, int n_in,
                              void* d_out, int out_size, void* d_ws, size_t ws_size,
                              hipStream_t stream) {
    const float* logits = (const float*)d_in[0];   // [E, H, 1] f32
    const int*   dst    = (const int*)d_in[1];     // [E] i32

    const int EH = in_sizes[0];
    const int E  = in_sizes[1];
    const int H  = EH / E;
    const int NH = out_size - EH;
    const int N  = NH / H;

    float* scores = (float*)d_out;          // [E,H]
    float* norm   = scores + EH;            // [N,H]

    const int nb1 = (N + SCAN_B - 1) / SCAN_B;
    const size_t need = ((size_t)3 * N + nb1 + E + 64) * sizeof(unsigned);

    if (H != 8 || ws_size < need) {
        // fallback: round-1 atomic scheme (3.2 MB workspace)
        unsigned* menc = (unsigned*)d_ws;
        hipMemsetAsync(menc, 0, (size_t)NH * 4, stream);
        hipMemsetAsync(norm, 0, (size_t)NH * 4, stream);
        int block = 256, grid = (EH + block - 1) / block;
        pass1_old<<<grid, block, 0, stream>>>(logits, dst, menc, EH, H);
        pass2_old<<<grid, block, 0, stream>>>(logits, dst, menc, scores, norm, EH, H);
        return;
    }

    unsigned* counts    = (unsigned*)d_ws;       // [N]
    unsigned* row_start = counts + N;            // [N]
    unsigned* row_cur   = row_start + N;         // [N]
    unsigned* partials  = row_cur + N;           // [nb1]
    unsigned* perm      = partials + ((nb1 + 63) & ~63); // [E]

    hipMemsetAsync(counts, 0, (size_t)N * 4, stream);

    const int gridE = (E + 255) / 256;
    const int gridW = (N * 64 + 255) / 256;      // wave per node

    k_hist   <<<gridE, 256, 0, stream>>>(dst, counts, E);
    k_scan1  <<<nb1, SCAN_B, 0, stream>>>(counts, row_start, partials, N);
    k_scan2  <<<1, 1024, 0, stream>>>(partials, nb1);
    k_scan3  <<<nb1, SCAN_B, 0, stream>>>(row_start, partials, row_cur, N);
    k_scatter<<<gridE, 256, 0, stream>>>(dst, row_cur, perm, E);
    k_node   <<<gridW, 256, 0, stream>>>(logits, perm, row_start, counts,
                                         scores, norm, N);
}